// Round 20
// baseline (300.372 us; speedup 1.0000x reference)
//
#include <hip/hip_runtime.h>
#include <hip/hip_fp16.h>

#define NN 100000
#define EE 600000
#define XSB 288          // bf16 feature row stride; layout: [x(6)|pad(26)|x1|x2|x3|x4], 64B-aligned
#define SCAN_B 2048
#define LOG2E 1.44269504f
#define SCAT_BLKS 2344   // ceil(EE/256)

typedef __attribute__((ext_vector_type(8))) short s16x8;
typedef __attribute__((ext_vector_type(4))) float f32x4;

__device__ inline unsigned short f2b(float f) {   // fp32 -> bf16 RNE
    unsigned u = __float_as_uint(f);
    u += 0x7fffu + ((u >> 16) & 1u);
    return (unsigned short)(u >> 16);
}

__device__ inline void accum4(float* d, float* s, const uint4& r) {
    const unsigned* u = (const unsigned*)&r;
#pragma unroll
    for (int ch = 0; ch < 4; ch++) {
        d[ch] += __uint_as_float(u[ch] << 16);
        s[ch] += __uint_as_float(u[ch] & 0xFFFF0000u);
    }
}

// xb-column k -> weight row: k<6 -> k ; k>=32 -> k-26 ; pad band [6,32) zero.
__device__ inline void wconv_elem(int idx, int fin,
                                  const float* wlin, const float* wsrc,
                                  const float* wpos, unsigned short* wt) {
    int ks = idx / 6144;          // 192*32
    int rem = idx - ks * 6144;
    int col = rem >> 5, kk = rem & 31;
    int k = ks * 32 + kk;
    int row = (k < 6) ? k : k - 26;
    float val = 0.f;
    if (k < 6 || (k >= 32 && row < fin)) {
        int m = col >> 6, c = col & 63;
        const float* W = (m == 0) ? wlin : (m == 1) ? wsrc : wpos;
        val = W[row * 64 + c];
    }
    wt[idx] = f2b(val);
}

// ---------------- fused setup (cheap form) ----------------
#define O0 1600000                // 100k*16 (2 cols per thread)
#define O1 1606144                // +192*32   wt0
#define O2 1624576                // +192*96   wt1
#define O3 1655296                // +192*160  wt2
#define O4 1698304                // +192*224  wt3
#define O5 1716736                // +64*288   w1t
#define O6 2316736                // +EE       hist
#define O7 2316800                // +64       dummy row

__global__ __launch_bounds__(256) void k_setup(
    const float* __restrict__ x, const int* __restrict__ ei,
    const float* __restrict__ wl0, const float* __restrict__ ws0, const float* __restrict__ wp0,
    const float* __restrict__ wl1, const float* __restrict__ ws1, const float* __restrict__ wp1,
    const float* __restrict__ wl2, const float* __restrict__ ws2, const float* __restrict__ wp2,
    const float* __restrict__ wl3, const float* __restrict__ ws3, const float* __restrict__ wp3,
    const float* __restrict__ w1,
    unsigned short* __restrict__ xb,
    unsigned short* __restrict__ wt0, unsigned short* __restrict__ wt1,
    unsigned short* __restrict__ wt2, unsigned short* __restrict__ wt3,
    unsigned short* __restrict__ w1t, int* __restrict__ deg,
    unsigned* __restrict__ vg) {
    int i = blockIdx.x * 256 + threadIdx.x;
    if (i < O0) {
        int n = i >> 4, c = (i & 15) * 2;    // cols c, c+1
        unsigned lo = (c < 6)     ? (unsigned)f2b(x[n * 6 + c])     : 0u;
        unsigned hi = (c + 1 < 6) ? (unsigned)f2b(x[n * 6 + c + 1]) : 0u;
        *(unsigned*)&xb[(size_t)n * XSB + c] = lo | (hi << 16);
    } else if (i < O1) {
        wconv_elem(i - O0, 6, wl0, ws0, wp0, wt0);
    } else if (i < O2) {
        wconv_elem(i - O1, 70, wl1, ws1, wp1, wt1);
    } else if (i < O3) {
        wconv_elem(i - O2, 134, wl2, ws2, wp2, wt2);
    } else if (i < O4) {
        wconv_elem(i - O3, 198, wl3, ws3, wp3, wt3);
    } else if (i < O5) {
        int idx = i - O4;                 // 64*288, k = xb column
        int col = idx / 288, k = idx - col * 288;
        int row = (k < 6) ? k : k - 26;
        bool valid = (k < 6) || (k >= 32 && row < 262);
        w1t[idx] = f2b(valid ? w1[row * 64 + col] : 0.f);
    } else if (i < O6) {
        atomicAdd(&deg[ei[EE + (i - O5)]], 1);   // dst-degree histogram
    } else if (i < O7) {
        vg[(size_t)NN * 64 + (i - O6)] = 0u;     // dummy row: (P,PG) = (0,0)
    }
}

// ---------------- single-pass CSR scan with decoupled lookback ----------------
// 49 blocks (always co-resident). Block b publishes its total (fence+flag);
// wave-0 lanes t<b spin on earlier flags, butterfly-sum. deg stays in registers.

__global__ __launch_bounds__(256) void k_scan(
    const int* __restrict__ deg, int* __restrict__ rowptr, int* __restrict__ cursor,
    int* __restrict__ bsum, int* __restrict__ bflag) {
    __shared__ int sh[256];
    __shared__ int soff;
    int b = blockIdx.x, t = threadIdx.x;
    int base = b * SCAN_B + t * 8;
    int vals[8], dv[8];
    int s = 0;
#pragma unroll
    for (int j = 0; j < 8; j++) {
        int i = base + j;
        dv[j] = (i < NN) ? deg[i] : 0;
        s += dv[j];
        vals[j] = s;
    }
    sh[t] = s;
    __syncthreads();
    for (int off = 1; off < 256; off <<= 1) {
        int vv = (t >= off) ? sh[t - off] : 0;
        __syncthreads();
        sh[t] += vv;
        __syncthreads();
    }
    int excl = (t > 0) ? sh[t - 1] : 0;
    if (t == 255) {
        bsum[b] = sh[255];
        __threadfence();
        atomicExch(&bflag[b], 1);
    }
    if (t < 64) {
        int v = 0;
        if (t < b) {                      // b <= 48 < 64
            while (atomicAdd(&bflag[t], 0) == 0) {}
            __threadfence();
            v = bsum[t];
        }
#pragma unroll
        for (int m = 1; m < 64; m <<= 1) v += __shfl_xor(v, m);
        if (t == 0) soff = v;
    }
    __syncthreads();
    int off = soff;
#pragma unroll
    for (int j = 0; j < 8; j++) {
        int i = base + j;
        if (i < NN) {
            int incl = vals[j] + excl + off;
            rowptr[i + 1] = incl;
            cursor[i] = incl - dv[j];
        }
    }
    if (b == 0 && t == 0) rowptr[0] = 0;
}

// ---------------- proj device body (XOR-swizzled LDS weights) ----------------
// P = 2^(-(a_src+p)*log2e), PG = P*(h-p) packed bf16|bf16 ; qh = half(p+b_pos).

template <int KP>
__device__ inline void proj_body(
    const unsigned short* __restrict__ xb, const unsigned short* __restrict__ wt,
    const float* __restrict__ bpos,
    unsigned* __restrict__ vg, __half* __restrict__ qh,
    short* wl, int row_blk) {
    const int t = threadIdx.x;
    const int w = t >> 6, l = t & 63;
    const int lo = l & 15, hi = l >> 4;
    const int row_w = row_blk + w * 32;

    f32x4 acc[2][12];
#pragma unroll
    for (int a = 0; a < 2; a++)
#pragma unroll
        for (int i = 0; i < 12; i++) acc[a][i] = (f32x4)0.f;

    const unsigned short* arow0 = xb + (size_t)(row_w + lo) * XSB;
    const unsigned short* arow1 = xb + (size_t)(row_w + 16 + lo) * XSB;
#pragma unroll
    for (int ks = 0; ks < KP / 32; ks++) {
        __syncthreads();
        {
            const uint4* src = (const uint4*)wt + (size_t)ks * 768;
            uint4* dst = (uint4*)wl;
#pragma unroll
            for (int i = 0; i < 3; i++) {
                int idx = i * 256 + t;
                dst[idx ^ ((idx >> 3) & 7)] = src[idx];
            }
        }
        __syncthreads();
        s16x8 af0 = *(const s16x8*)(arow0 + ks * 32 + hi * 8);
        s16x8 af1 = *(const s16x8*)(arow1 + ks * 32 + hi * 8);
#pragma unroll
        for (int ct = 0; ct < 12; ct++) {
            int ridx = (ct * 16 + lo) * 4 + hi;
            s16x8 bf = *(const s16x8*)&wl[(size_t)(ridx ^ ((ridx >> 3) & 7)) * 8];
            acc[0][ct] = __builtin_amdgcn_mfma_f32_16x16x32_bf16(af0, bf, acc[0][ct], 0, 0, 0);
            acc[1][ct] = __builtin_amdgcn_mfma_f32_16x16x32_bf16(af1, bf, acc[1][ct], 0, 0, 0);
        }
    }

#pragma unroll
    for (int tile = 0; tile < 2; tile++) {
#pragma unroll
        for (int r = 0; r < 4; r++) {
            int node = row_w + tile * 16 + hi * 4 + r;
            if (node < NN) {
#pragma unroll
                for (int j = 0; j < 4; j++) {
                    int c = j * 16 + lo;
                    float h  = acc[tile][0 + j][r];
                    float as = acc[tile][4 + j][r];
                    float p  = acc[tile][8 + j][r];
                    size_t o = (size_t)node * 64 + c;
                    float P = __builtin_amdgcn_exp2f(-(as + p) * LOG2E);
                    vg[o] = (unsigned)f2b(P) | ((unsigned)f2b(P * (h - p)) << 16);
                    qh[o] = __float2half(p + bpos[c]);
                }
            }
        }
    }
}

template <int KP>
__global__ __launch_bounds__(256) void k_projm(
    const unsigned short* __restrict__ xb, const unsigned short* __restrict__ wt,
    const float* __restrict__ bpos,
    unsigned* __restrict__ vg, __half* __restrict__ qh) {
    __shared__ short wl[192 * 32];
    proj_body<KP>(xb, wt, bpos, vg, qh, wl, blockIdx.x * 128);
}

// ---------------- MERGED scatter + proj1 (independent phases, block-range split) ----
// Blocks 0..SCAT_BLKS-1: CSR scatter (atomic-heavy). Blocks SCAT_BLKS..: proj layer 1
// (MFMA-heavy). No data dependence between phases -> co-resident waves overlap
// memory/atomic work with matrix work; saves one dispatch+drain.

__global__ __launch_bounds__(256) void k_scatproj(
    const int* __restrict__ ei, int* __restrict__ cursor, int* __restrict__ csrc,
    const unsigned short* __restrict__ xb, const unsigned short* __restrict__ wt0,
    const float* __restrict__ bp0,
    unsigned* __restrict__ vg, __half* __restrict__ qh) {
    __shared__ short wl[192 * 32];
    if (blockIdx.x < SCAT_BLKS) {
        int e = blockIdx.x * 256 + threadIdx.x;
        if (e < EE) {
            int d = ei[EE + e];
            int pos = atomicAdd(&cursor[d], 1);
            csrc[pos] = ei[e];
        }
        return;
    }
    proj_body<32>(xb, wt0, bp0, vg, qh, wl, (blockIdx.x - SCAT_BLKS) * 128);
}

// ---------------- MFMA MLP-1 (262->64) fused with MLP-2 (64->10) ----------------

__global__ __launch_bounds__(256) void k_mlp1f(
    const unsigned short* __restrict__ xb, const unsigned short* __restrict__ w1t,
    const float* __restrict__ b1, const float* __restrict__ w2,
    const float* __restrict__ b2, float* __restrict__ out) {
    __shared__ float w2l[64][10];
    __shared__ float b2l[10];
    __shared__ float b1l[64];
    for (int t = threadIdx.x; t < 714; t += 256) {
        if (t < 640) ((float*)w2l)[t] = w2[t];
        else if (t < 650) b2l[t - 640] = b2[t - 640];
        else b1l[t - 650] = b1[t - 650];
    }
    __syncthreads();

    const int w = threadIdx.x >> 6, l = threadIdx.x & 63;
    const int lo = l & 15, hi = l >> 4;
    const int row_w = blockIdx.x * 256 + w * 64;

    f32x4 acc[4][4];
#pragma unroll
    for (int a = 0; a < 4; a++)
#pragma unroll
        for (int b = 0; b < 4; b++) acc[a][b] = (f32x4)0.f;

#pragma unroll
    for (int ks = 0; ks < 9; ks++) {
        const int k0 = ks * 32 + hi * 8;
        s16x8 bf[4];
#pragma unroll
        for (int ct = 0; ct < 4; ct++)
            bf[ct] = *(const s16x8*)(w1t + (size_t)(ct * 16 + lo) * 288 + k0);
#pragma unroll
        for (int rt = 0; rt < 4; rt++) {
            s16x8 af = *(const s16x8*)(xb + (size_t)(row_w + rt * 16 + lo) * XSB + k0);
#pragma unroll
            for (int ct = 0; ct < 4; ct++)
                acc[rt][ct] = __builtin_amdgcn_mfma_f32_16x16x32_bf16(af, bf[ct], acc[rt][ct], 0, 0, 0);
        }
    }

#pragma unroll
    for (int rt = 0; rt < 4; rt++) {
#pragma unroll
        for (int r = 0; r < 4; r++) {
            int node = row_w + rt * 16 + hi * 4 + r;
            float po[10];
#pragma unroll
            for (int o = 0; o < 10; o++) po[o] = 0.f;
#pragma unroll
            for (int ct = 0; ct < 4; ct++) {
                int c = ct * 16 + lo;
                float hv = acc[rt][ct][r] + b1l[c];
#pragma unroll
                for (int o = 0; o < 10; o++) po[o] = fmaf(hv, w2l[c][o], po[o]);
            }
#pragma unroll
            for (int m = 1; m < 16; m <<= 1)
#pragma unroll
                for (int o = 0; o < 10; o++) po[o] += __shfl_xor(po[o], m);
            if (lo == 0 && node < NN) {
                float* op = out + (size_t)node * 10;
#pragma unroll
                for (int o = 0; o < 5; o++)
                    *(float2*)(op + o * 2) = make_float2(po[o * 2] + b2l[o * 2],
                                                         po[o * 2 + 1] + b2l[o * 2 + 1]);
            }
        }
    }
}

// ---------------- edge aggregation: group-per-node, preloaded indices ----------------

template <int RELU>
__global__ __launch_bounds__(256) void k_edge(
    const uint4* __restrict__ vg,     // [NN+1][16] uint4 = 64 channels of bf16(P)|bf16(PG)<<16
    const uint2* __restrict__ qh,     // [NN][16] uint2 = 64 channels of half q
    const int* __restrict__ rowptr, const int* __restrict__ csrc,
    unsigned short* __restrict__ xb, int col) {
    int l = threadIdx.x & 63;
    int g = l >> 4, lg = l & 15, gbase = g * 16;
    int node = (blockIdx.x * 4 + (threadIdx.x >> 6)) * 4 + g;   // NN % 16 == 0
    int b = rowptr[node], e = rowptr[node + 1];
    int deg = e - b;
    int pre = csrc[b + lg];                                // unconditional (+16 slack)
    uint2 qr = qh[(size_t)node * 16 + lg];                 // overlaps with pre load
    float d[4] = {0.f, 0.f, 0.f, 0.f};
    float s[4] = {0.f, 0.f, 0.f, 0.f};

    int it = 0;
    int degc = min(deg, 16);
    for (; it < degc; it += 4) {
        int i0 = (it < deg)     ? __shfl(pre, gbase + it)     : NN;
        int i1 = (it + 1 < deg) ? __shfl(pre, gbase + it + 1) : NN;
        int i2 = (it + 2 < deg) ? __shfl(pre, gbase + it + 2) : NN;
        int i3 = (it + 3 < deg) ? __shfl(pre, gbase + it + 3) : NN;
        uint4 r0 = vg[(size_t)i0 * 16 + lg];
        uint4 r1 = vg[(size_t)i1 * 16 + lg];
        uint4 r2 = vg[(size_t)i2 * 16 + lg];
        uint4 r3 = vg[(size_t)i3 * 16 + lg];
        accum4(d, s, r0); accum4(d, s, r1); accum4(d, s, r2); accum4(d, s, r3);
    }
    for (; it < deg; ++it) {                               // rare tail: deg > 16
        uint4 r0 = vg[(size_t)csrc[b + it] * 16 + lg];
        accum4(d, s, r0);
    }

    float2 q01 = __half22float2(*(const __half2*)&qr.x);
    float2 q23 = __half22float2(*(const __half2*)&qr.y);
    float qv[4] = {q01.x, q01.y, q23.x, q23.y};
    float o[4];
#pragma unroll
    for (int ch = 0; ch < 4; ch++) {
        float v = (s[ch] + qv[ch] * d[ch]) / (d[ch] + 1e-16f);
        if (RELU) v = (v > 0.f) ? v : 0.01f * v;
        o[ch] = v;
    }
    unsigned p01 = (unsigned)f2b(o[0]) | ((unsigned)f2b(o[1]) << 16);
    unsigned p23 = (unsigned)f2b(o[2]) | ((unsigned)f2b(o[3]) << 16);
    *(uint2*)(xb + (size_t)node * XSB + col + 4 * lg) = make_uint2(p01, p23);
}

// ---------------- launch ----------------

extern "C" void kernel_launch(void* const* d_in, const int* in_sizes, int n_in,
                              void* d_out, int out_size, void* d_ws, size_t ws_size,
                              hipStream_t stream) {
    const float* x = (const float*)d_in[0];
    const int* ei = (const int*)d_in[1];
    const float* W[4][4];
    const float* BP[4];
    int base = 2;
    for (int l = 0; l < 4; l++) {
        for (int m = 0; m < 4; m++) W[l][m] = (const float*)d_in[base + m];
        BP[l] = (const float*)d_in[base + 4];
        base += 5;
    }
    const float* w1 = (const float*)d_in[22];
    const float* b1 = (const float*)d_in[23];
    const float* w2 = (const float*)d_in[24];
    const float* b2 = (const float*)d_in[25];

    char* wsp = (char*)d_ws;
    size_t off = 0;
    auto alloc = [&](size_t bytes) {
        void* p = wsp + off;
        off += (bytes + 255) & ~(size_t)255;
        return p;
    };
    unsigned short* xb = (unsigned short*)alloc((size_t)(NN + 256) * XSB * 2);
    unsigned* vg = (unsigned*)alloc((size_t)(NN + 1) * 64 * 4);   // +1 dummy row
    __half* qh = (__half*)alloc((size_t)NN * 64 * 2);
    int* deg = (int*)alloc((size_t)NN * 4);       // deg + bflag zeroed together
    int* bflag = (int*)alloc(256 * 4);
    int* bsum = (int*)alloc(256 * 4);
    int* rowptr = (int*)alloc((size_t)(NN + 1) * 4);
    int* cursor = (int*)alloc((size_t)NN * 4);
    int* csrc = (int*)alloc((size_t)(EE + 16) * 4);
    const int KPv[4] = {32, 96, 160, 224};
    unsigned short* wt[4];
    for (int l = 0; l < 4; l++) wt[l] = (unsigned short*)alloc((size_t)192 * KPv[l] * 2);
    unsigned short* w1t = (unsigned short*)alloc((size_t)64 * 288 * 2);

    // zero deg (400000B, padded to 400128) + bflag (1024B) in one memset
    hipMemsetAsync(deg, 0, 400128 + 1024, stream);
    k_setup<<<(O7 + 255) / 256, 256, 0, stream>>>(
        x, ei,
        W[0][0], W[0][1], W[0][3],
        W[1][0], W[1][1], W[1][3],
        W[2][0], W[2][1], W[2][3],
        W[3][0], W[3][1], W[3][3], w1,
        xb, wt[0], wt[1], wt[2], wt[3], w1t, deg, vg);

    int nb = (NN + SCAN_B - 1) / SCAN_B;  // 49
    k_scan<<<nb, 256, 0, stream>>>(deg, rowptr, cursor, bsum, bflag);

    const int gProj = (NN + 127) / 128;  // 782
    const int gEdge = NN / 16;           // 6250 (NN % 16 == 0)
    const uint4* vgu = (const uint4*)vg;
    const uint2* qh2 = (const uint2*)qh;

    // scatter (blocks 0..2343) || proj1 (blocks 2344..3125) — independent phases
    k_scatproj<<<SCAT_BLKS + gProj, 256, 0, stream>>>(
        ei, cursor, csrc, xb, wt[0], BP[0], vg, qh);

    k_edge<0><<<gEdge, 256, 0, stream>>>(vgu, qh2, rowptr, csrc, xb, 32);
    k_projm<96><<<gProj, 256, 0, stream>>>(xb, wt[1], BP[1], vg, qh);
    k_edge<1><<<gEdge, 256, 0, stream>>>(vgu, qh2, rowptr, csrc, xb, 96);
    k_projm<160><<<gProj, 256, 0, stream>>>(xb, wt[2], BP[2], vg, qh);
    k_edge<1><<<gEdge, 256, 0, stream>>>(vgu, qh2, rowptr, csrc, xb, 160);
    k_projm<224><<<gProj, 256, 0, stream>>>(xb, wt[3], BP[3], vg, qh);
    k_edge<1><<<gEdge, 256, 0, stream>>>(vgu, qh2, rowptr, csrc, xb, 224);

    k_mlp1f<<<(NN + 255) / 256, 256, 0, stream>>>(xb, w1t, b1, w2, b2, (float*)d_out);
}

// Round 21
// 289.075 us; speedup vs baseline: 1.0391x; 1.0391x over previous
//
#include <hip/hip_runtime.h>
#include <hip/hip_fp16.h>

#define NN 100000
#define EE 600000
#define XSB 288          // bf16 feature row stride; layout: [x(6)|pad(26)|x1|x2|x3|x4], 64B-aligned
#define LOG2E 1.44269504f

typedef __attribute__((ext_vector_type(8))) short s16x8;
typedef __attribute__((ext_vector_type(4))) float f32x4;

__device__ inline unsigned short f2b(float f) {   // fp32 -> bf16 RNE
    unsigned u = __float_as_uint(f);
    u += 0x7fffu + ((u >> 16) & 1u);
    return (unsigned short)(u >> 16);
}

__device__ inline void accum4(float* d, float* s, const uint4& r) {
    const unsigned* u = (const unsigned*)&r;
#pragma unroll
    for (int ch = 0; ch < 4; ch++) {
        d[ch] += __uint_as_float(u[ch] << 16);
        s[ch] += __uint_as_float(u[ch] & 0xFFFF0000u);
    }
}

// xb-column k -> weight row: k<6 -> k ; k>=32 -> k-26 ; pad band [6,32) zero.
__device__ inline void wconv_elem(int idx, int fin,
                                  const float* wlin, const float* wsrc,
                                  const float* wpos, unsigned short* wt) {
    int ks = idx / 6144;          // 192*32
    int rem = idx - ks * 6144;
    int col = rem >> 5, kk = rem & 31;
    int k = ks * 32 + kk;
    int row = (k < 6) ? k : k - 26;
    float val = 0.f;
    if (k < 6 || (k >= 32 && row < fin)) {
        int m = col >> 6, c = col & 63;
        const float* W = (m == 0) ? wlin : (m == 1) ? wsrc : wpos;
        val = W[row * 64 + c];
    }
    wt[idx] = f2b(val);
}

// ---------------- fused setup: xb init + weights + ONE-PASS ELL adjacency build ----------------
// R6: per edge: pos = atomicAdd(deg[dst]); pos<16 -> ell[dst*16+pos]=src ; else -> overflow list.
// (Replaces histogram + prefix scan + scatter: one atomic pass instead of two, no scan.)
// deg + ovfc zeroed by hipMemsetAsync before this kernel.
#define O0 1600000                // 100k*16 (2 cols per thread)
#define O1 1606144                // +192*32   wt0
#define O2 1624576                // +192*96   wt1
#define O3 1655296                // +192*160  wt2
#define O4 1698304                // +192*224  wt3
#define O5 1716736                // +64*288   w1t
#define O6 2316736                // +EE       ELL build
#define O7 2316800                // +64       dummy vg row

__global__ __launch_bounds__(256) void k_setup(
    const float* __restrict__ x, const int* __restrict__ ei,
    const float* __restrict__ wl0, const float* __restrict__ ws0, const float* __restrict__ wp0,
    const float* __restrict__ wl1, const float* __restrict__ ws1, const float* __restrict__ wp1,
    const float* __restrict__ wl2, const float* __restrict__ ws2, const float* __restrict__ wp2,
    const float* __restrict__ wl3, const float* __restrict__ ws3, const float* __restrict__ wp3,
    const float* __restrict__ w1,
    unsigned short* __restrict__ xb,
    unsigned short* __restrict__ wt0, unsigned short* __restrict__ wt1,
    unsigned short* __restrict__ wt2, unsigned short* __restrict__ wt3,
    unsigned short* __restrict__ w1t, int* __restrict__ deg,
    int* __restrict__ ell, int* __restrict__ ovfc, int* __restrict__ ovf,
    unsigned* __restrict__ vg) {
    int i = blockIdx.x * 256 + threadIdx.x;
    if (i < O0) {
        int n = i >> 4, c = (i & 15) * 2;    // cols c, c+1
        unsigned lo = (c < 6)     ? (unsigned)f2b(x[n * 6 + c])     : 0u;
        unsigned hi = (c + 1 < 6) ? (unsigned)f2b(x[n * 6 + c + 1]) : 0u;
        *(unsigned*)&xb[(size_t)n * XSB + c] = lo | (hi << 16);
    } else if (i < O1) {
        wconv_elem(i - O0, 6, wl0, ws0, wp0, wt0);
    } else if (i < O2) {
        wconv_elem(i - O1, 70, wl1, ws1, wp1, wt1);
    } else if (i < O3) {
        wconv_elem(i - O2, 134, wl2, ws2, wp2, wt2);
    } else if (i < O4) {
        wconv_elem(i - O3, 198, wl3, ws3, wp3, wt3);
    } else if (i < O5) {
        int idx = i - O4;                 // 64*288, k = xb column
        int col = idx / 288, k = idx - col * 288;
        int row = (k < 6) ? k : k - 26;
        bool valid = (k < 6) || (k >= 32 && row < 262);
        w1t[idx] = f2b(valid ? w1[row * 64 + col] : 0.f);
    } else if (i < O6) {
        int e = i - O5;
        int d = ei[EE + e];
        int pos = atomicAdd(&deg[d], 1);
        if (pos < 16) {
            ell[d * 16 + pos] = ei[e];
        } else {                          // rare: deg > 16 (P ~ 1e-4 per node)
            int k = atomicAdd(ovfc, 1);
            ovf[2 * k] = d;
            ovf[2 * k + 1] = ei[e];
        }
    } else if (i < O7) {
        vg[(size_t)NN * 64 + (i - O6)] = 0u;     // dummy row: (P,PG) = (0,0)
    }
}

// ---------------- proj: MFMA 3-way, XOR-swizzled LDS weights ----------------
// P = 2^(-(a_src+p)*log2e), PG = P*(h-p) packed bf16|bf16 ; qh = half(p+b_pos).

template <int KP>
__global__ __launch_bounds__(256) void k_projm(
    const unsigned short* __restrict__ xb, const unsigned short* __restrict__ wt,
    const float* __restrict__ bpos,
    unsigned* __restrict__ vg, __half* __restrict__ qh) {
    __shared__ short wl[192 * 32];
    const int t = threadIdx.x;
    const int w = t >> 6, l = t & 63;
    const int lo = l & 15, hi = l >> 4;
    const int row_w = blockIdx.x * 128 + w * 32;

    f32x4 acc[2][12];
#pragma unroll
    for (int a = 0; a < 2; a++)
#pragma unroll
        for (int i = 0; i < 12; i++) acc[a][i] = (f32x4)0.f;

    const unsigned short* arow0 = xb + (size_t)(row_w + lo) * XSB;
    const unsigned short* arow1 = xb + (size_t)(row_w + 16 + lo) * XSB;
#pragma unroll
    for (int ks = 0; ks < KP / 32; ks++) {
        __syncthreads();
        {
            const uint4* src = (const uint4*)wt + (size_t)ks * 768;
            uint4* dst = (uint4*)wl;
#pragma unroll
            for (int i = 0; i < 3; i++) {
                int idx = i * 256 + t;
                dst[idx ^ ((idx >> 3) & 7)] = src[idx];
            }
        }
        __syncthreads();
        s16x8 af0 = *(const s16x8*)(arow0 + ks * 32 + hi * 8);
        s16x8 af1 = *(const s16x8*)(arow1 + ks * 32 + hi * 8);
#pragma unroll
        for (int ct = 0; ct < 12; ct++) {
            int ridx = (ct * 16 + lo) * 4 + hi;
            s16x8 bf = *(const s16x8*)&wl[(size_t)(ridx ^ ((ridx >> 3) & 7)) * 8];
            acc[0][ct] = __builtin_amdgcn_mfma_f32_16x16x32_bf16(af0, bf, acc[0][ct], 0, 0, 0);
            acc[1][ct] = __builtin_amdgcn_mfma_f32_16x16x32_bf16(af1, bf, acc[1][ct], 0, 0, 0);
        }
    }

#pragma unroll
    for (int tile = 0; tile < 2; tile++) {
#pragma unroll
        for (int r = 0; r < 4; r++) {
            int node = row_w + tile * 16 + hi * 4 + r;
            if (node < NN) {
#pragma unroll
                for (int j = 0; j < 4; j++) {
                    int c = j * 16 + lo;
                    float h  = acc[tile][0 + j][r];
                    float as = acc[tile][4 + j][r];
                    float p  = acc[tile][8 + j][r];
                    size_t o = (size_t)node * 64 + c;
                    float P = __builtin_amdgcn_exp2f(-(as + p) * LOG2E);
                    vg[o] = (unsigned)f2b(P) | ((unsigned)f2b(P * (h - p)) << 16);
                    qh[o] = __float2half(p + bpos[c]);
                }
            }
        }
    }
}

// ---------------- MFMA MLP-1 (262->64) fused with MLP-2 (64->10) ----------------

__global__ __launch_bounds__(256) void k_mlp1f(
    const unsigned short* __restrict__ xb, const unsigned short* __restrict__ w1t,
    const float* __restrict__ b1, const float* __restrict__ w2,
    const float* __restrict__ b2, float* __restrict__ out) {
    __shared__ float w2l[64][10];
    __shared__ float b2l[10];
    __shared__ float b1l[64];
    for (int t = threadIdx.x; t < 714; t += 256) {
        if (t < 640) ((float*)w2l)[t] = w2[t];
        else if (t < 650) b2l[t - 640] = b2[t - 640];
        else b1l[t - 650] = b1[t - 650];
    }
    __syncthreads();

    const int w = threadIdx.x >> 6, l = threadIdx.x & 63;
    const int lo = l & 15, hi = l >> 4;
    const int row_w = blockIdx.x * 256 + w * 64;

    f32x4 acc[4][4];
#pragma unroll
    for (int a = 0; a < 4; a++)
#pragma unroll
        for (int b = 0; b < 4; b++) acc[a][b] = (f32x4)0.f;

#pragma unroll
    for (int ks = 0; ks < 9; ks++) {
        const int k0 = ks * 32 + hi * 8;
        s16x8 bf[4];
#pragma unroll
        for (int ct = 0; ct < 4; ct++)
            bf[ct] = *(const s16x8*)(w1t + (size_t)(ct * 16 + lo) * 288 + k0);
#pragma unroll
        for (int rt = 0; rt < 4; rt++) {
            s16x8 af = *(const s16x8*)(xb + (size_t)(row_w + rt * 16 + lo) * XSB + k0);
#pragma unroll
            for (int ct = 0; ct < 4; ct++)
                acc[rt][ct] = __builtin_amdgcn_mfma_f32_16x16x32_bf16(af, bf[ct], acc[rt][ct], 0, 0, 0);
        }
    }

#pragma unroll
    for (int rt = 0; rt < 4; rt++) {
#pragma unroll
        for (int r = 0; r < 4; r++) {
            int node = row_w + rt * 16 + hi * 4 + r;
            float po[10];
#pragma unroll
            for (int o = 0; o < 10; o++) po[o] = 0.f;
#pragma unroll
            for (int ct = 0; ct < 4; ct++) {
                int c = ct * 16 + lo;
                float hv = acc[rt][ct][r] + b1l[c];
#pragma unroll
                for (int o = 0; o < 10; o++) po[o] = fmaf(hv, w2l[c][o], po[o]);
            }
#pragma unroll
            for (int m = 1; m < 16; m <<= 1)
#pragma unroll
                for (int o = 0; o < 10; o++) po[o] += __shfl_xor(po[o], m);
            if (lo == 0 && node < NN) {
                float* op = out + (size_t)node * 10;
#pragma unroll
                for (int o = 0; o < 5; o++)
                    *(float2*)(op + o * 2) = make_float2(po[o * 2] + b2l[o * 2],
                                                         po[o * 2 + 1] + b2l[o * 2 + 1]);
            }
        }
    }
}

// ---------------- edge aggregation: group-per-node, ELL adjacency ----------------
// Wave = 4 nodes; lane lg owns channels 4lg..4lg+3. Sources come from the node's
// ELL row (one aligned 64B group load), broadcast via shfl; 4 independent 256B
// gathers/iter. deg>16 tail scans the tiny overflow list (L2-hot, ~dozen entries).

template <int RELU>
__global__ __launch_bounds__(256) void k_edge(
    const uint4* __restrict__ vg,     // [NN+1][16] uint4 = 64 channels of bf16(P)|bf16(PG)<<16
    const uint2* __restrict__ qh,     // [NN][16] uint2 = 64 channels of half q
    const int* __restrict__ deg, const int* __restrict__ ell,
    const int* __restrict__ ovfc, const int* __restrict__ ovf,
    unsigned short* __restrict__ xb, int col) {
    int l = threadIdx.x & 63;
    int g = l >> 4, lg = l & 15, gbase = g * 16;
    int node = (blockIdx.x * 4 + (threadIdx.x >> 6)) * 4 + g;   // NN % 16 == 0
    int dg = deg[node];
    int pre = ell[node * 16 + lg];                         // aligned 64B group read
    uint2 qr = qh[(size_t)node * 16 + lg];                 // overlaps with pre load
    float d[4] = {0.f, 0.f, 0.f, 0.f};
    float s[4] = {0.f, 0.f, 0.f, 0.f};

    int degc = min(dg, 16);
    for (int it = 0; it < degc; it += 4) {
        int i0 = (it < dg)     ? __shfl(pre, gbase + it)     : NN;
        int i1 = (it + 1 < dg) ? __shfl(pre, gbase + it + 1) : NN;
        int i2 = (it + 2 < dg) ? __shfl(pre, gbase + it + 2) : NN;
        int i3 = (it + 3 < dg) ? __shfl(pre, gbase + it + 3) : NN;
        uint4 r0 = vg[(size_t)i0 * 16 + lg];
        uint4 r1 = vg[(size_t)i1 * 16 + lg];
        uint4 r2 = vg[(size_t)i2 * 16 + lg];
        uint4 r3 = vg[(size_t)i3 * 16 + lg];
        accum4(d, s, r0); accum4(d, s, r1); accum4(d, s, r2); accum4(d, s, r3);
    }
    if (dg > 16) {                                         // rare tail via overflow list
        int cnt = ovfc[0];
        for (int i = 0; i < cnt; i++) {
            if (ovf[2 * i] == node) {
                uint4 r0 = vg[(size_t)ovf[2 * i + 1] * 16 + lg];
                accum4(d, s, r0);
            }
        }
    }

    float2 q01 = __half22float2(*(const __half2*)&qr.x);
    float2 q23 = __half22float2(*(const __half2*)&qr.y);
    float qv[4] = {q01.x, q01.y, q23.x, q23.y};
    float o[4];
#pragma unroll
    for (int ch = 0; ch < 4; ch++) {
        float v = (s[ch] + qv[ch] * d[ch]) / (d[ch] + 1e-16f);
        if (RELU) v = (v > 0.f) ? v : 0.01f * v;
        o[ch] = v;
    }
    unsigned p01 = (unsigned)f2b(o[0]) | ((unsigned)f2b(o[1]) << 16);
    unsigned p23 = (unsigned)f2b(o[2]) | ((unsigned)f2b(o[3]) << 16);
    *(uint2*)(xb + (size_t)node * XSB + col + 4 * lg) = make_uint2(p01, p23);
}

// ---------------- launch ----------------

extern "C" void kernel_launch(void* const* d_in, const int* in_sizes, int n_in,
                              void* d_out, int out_size, void* d_ws, size_t ws_size,
                              hipStream_t stream) {
    const float* x = (const float*)d_in[0];
    const int* ei = (const int*)d_in[1];
    const float* W[4][4];
    const float* BP[4];
    int base = 2;
    for (int l = 0; l < 4; l++) {
        for (int m = 0; m < 4; m++) W[l][m] = (const float*)d_in[base + m];
        BP[l] = (const float*)d_in[base + 4];
        base += 5;
    }
    const float* w1 = (const float*)d_in[22];
    const float* b1 = (const float*)d_in[23];
    const float* w2 = (const float*)d_in[24];
    const float* b2 = (const float*)d_in[25];

    char* wsp = (char*)d_ws;
    size_t off = 0;
    auto alloc = [&](size_t bytes) {
        void* p = wsp + off;
        off += (bytes + 255) & ~(size_t)255;
        return p;
    };
    unsigned short* xb = (unsigned short*)alloc((size_t)(NN + 256) * XSB * 2);
    unsigned* vg = (unsigned*)alloc((size_t)(NN + 1) * 64 * 4);   // +1 dummy row
    __half* qh = (__half*)alloc((size_t)NN * 64 * 2);
    int* deg = (int*)alloc((size_t)NN * 4);       // deg (padded 400128) then ovfc: one memset
    int* ovfc = (int*)alloc(256);
    int* ell = (int*)alloc((size_t)NN * 16 * 4);
    int* ovf = (int*)alloc((size_t)2 * EE * 4);
    const int KPv[4] = {32, 96, 160, 224};
    unsigned short* wt[4];
    for (int l = 0; l < 4; l++) wt[l] = (unsigned short*)alloc((size_t)192 * KPv[l] * 2);
    unsigned short* w1t = (unsigned short*)alloc((size_t)64 * 288 * 2);

    // zero deg (400000B -> padded 400128) + ovfc (256B) in one memset
    hipMemsetAsync(deg, 0, 400128 + 256, stream);
    k_setup<<<(O7 + 255) / 256, 256, 0, stream>>>(
        x, ei,
        W[0][0], W[0][1], W[0][3],
        W[1][0], W[1][1], W[1][3],
        W[2][0], W[2][1], W[2][3],
        W[3][0], W[3][1], W[3][3], w1,
        xb, wt[0], wt[1], wt[2], wt[3], w1t, deg, ell, ovfc, ovf, vg);

    const int gProj = (NN + 127) / 128;  // 782
    const int gEdge = NN / 16;           // 6250 (NN % 16 == 0)
    const uint4* vgu = (const uint4*)vg;
    const uint2* qh2 = (const uint2*)qh;

    k_projm<32><<<gProj, 256, 0, stream>>>(xb, wt[0], BP[0], vg, qh);
    k_edge<0><<<gEdge, 256, 0, stream>>>(vgu, qh2, deg, ell, ovfc, ovf, xb, 32);
    k_projm<96><<<gProj, 256, 0, stream>>>(xb, wt[1], BP[1], vg, qh);
    k_edge<1><<<gEdge, 256, 0, stream>>>(vgu, qh2, deg, ell, ovfc, ovf, xb, 96);
    k_projm<160><<<gProj, 256, 0, stream>>>(xb, wt[2], BP[2], vg, qh);
    k_edge<1><<<gEdge, 256, 0, stream>>>(vgu, qh2, deg, ell, ovfc, ovf, xb, 160);
    k_projm<224><<<gProj, 256, 0, stream>>>(xb, wt[3], BP[3], vg, qh);
    k_edge<1><<<gEdge, 256, 0, stream>>>(vgu, qh2, deg, ell, ovfc, ovf, xb, 224);

    k_mlp1f<<<(NN + 255) / 256, 256, 0, stream>>>(xb, w1t, b1, w2, b2, (float*)d_out);
}

// Round 22
// 267.752 us; speedup vs baseline: 1.1218x; 1.0796x over previous
//
#include <hip/hip_runtime.h>
#include <hip/hip_fp16.h>

#define NN 100000
#define EE 600000
#define XSB 288          // bf16 feature row stride; layout: [x(6)|pad(26)|x1|x2|x3|x4], 64B-aligned
#define LOG2E 1.44269504f

typedef __attribute__((ext_vector_type(8))) short s16x8;
typedef __attribute__((ext_vector_type(4))) float f32x4;

__device__ inline unsigned short f2b(float f) {   // fp32 -> bf16 RNE
    unsigned u = __float_as_uint(f);
    u += 0x7fffu + ((u >> 16) & 1u);
    return (unsigned short)(u >> 16);
}

__device__ inline void accum4(float* d, float* s, const uint4& r) {
    const unsigned* u = (const unsigned*)&r;
#pragma unroll
    for (int ch = 0; ch < 4; ch++) {
        d[ch] += __uint_as_float(u[ch] << 16);
        s[ch] += __uint_as_float(u[ch] & 0xFFFF0000u);
    }
}

// xb-column k -> weight row: k<6 -> k ; k>=32 -> k-26 ; pad band [6,32) zero.
__device__ inline void wconv_elem(int idx, int fin,
                                  const float* wlin, const float* wsrc,
                                  const float* wpos, unsigned short* wt) {
    int ks = idx / 6144;          // 192*32
    int rem = idx - ks * 6144;
    int col = rem >> 5, kk = rem & 31;
    int k = ks * 32 + kk;
    int row = (k < 6) ? k : k - 26;
    float val = 0.f;
    if (k < 6 || (k >= 32 && row < fin)) {
        int m = col >> 6, c = col & 63;
        const float* W = (m == 0) ? wlin : (m == 1) ? wsrc : wpos;
        val = W[row * 64 + c];
    }
    wt[idx] = f2b(val);
}

// ---------------- fused setup: xb init + weights + ONE-PASS ELL build (4 edges/thread) ----
// R6: per thread, 4 independent chains {load dst/src, atomicAdd, store slot} -> 4x the
// memory-level parallelism of the 1-edge/thread version (which profiled latency-bound:
// VALUBusy 2%, occupancy 72%, 750 GB/s). deg + ovfc zeroed by hipMemsetAsync before.
#define O0 800000                 // 100k*8 (4 cols per thread, uint2 store)
#define O1 806144                 // +192*32   wt0
#define O2 824576                 // +192*96   wt1
#define O3 855296                 // +192*160  wt2
#define O4 898304                 // +192*224  wt3
#define O5 916736                 // +64*288   w1t
#define O6 1066736                // +EE/4     ELL build (4 edges/thread)
#define O7 1066800                // +64       dummy vg row

__global__ __launch_bounds__(256) void k_setup(
    const float* __restrict__ x, const int* __restrict__ ei,
    const float* __restrict__ wl0, const float* __restrict__ ws0, const float* __restrict__ wp0,
    const float* __restrict__ wl1, const float* __restrict__ ws1, const float* __restrict__ wp1,
    const float* __restrict__ wl2, const float* __restrict__ ws2, const float* __restrict__ wp2,
    const float* __restrict__ wl3, const float* __restrict__ ws3, const float* __restrict__ wp3,
    const float* __restrict__ w1,
    unsigned short* __restrict__ xb,
    unsigned short* __restrict__ wt0, unsigned short* __restrict__ wt1,
    unsigned short* __restrict__ wt2, unsigned short* __restrict__ wt3,
    unsigned short* __restrict__ w1t, int* __restrict__ deg,
    int* __restrict__ ell, int* __restrict__ ovfc, int* __restrict__ ovf,
    unsigned* __restrict__ vg) {
    int i = blockIdx.x * 256 + threadIdx.x;
    if (i < O0) {
        int n = i >> 3, c = (i & 7) * 4;     // cols c..c+3 (8B-aligned)
        unsigned v0 = 0u, v1 = 0u;
        if (c < 6) {
            v0 = (unsigned)f2b(x[n * 6 + c]) |
                 ((c + 1 < 6 ? (unsigned)f2b(x[n * 6 + c + 1]) : 0u) << 16);
            if (c + 2 < 6)
                v1 = (unsigned)f2b(x[n * 6 + c + 2]) |
                     ((c + 3 < 6 ? (unsigned)f2b(x[n * 6 + c + 3]) : 0u) << 16);
        }
        *(uint2*)&xb[(size_t)n * XSB + c] = make_uint2(v0, v1);
    } else if (i < O1) {
        wconv_elem(i - O0, 6, wl0, ws0, wp0, wt0);
    } else if (i < O2) {
        wconv_elem(i - O1, 70, wl1, ws1, wp1, wt1);
    } else if (i < O3) {
        wconv_elem(i - O2, 134, wl2, ws2, wp2, wt2);
    } else if (i < O4) {
        wconv_elem(i - O3, 198, wl3, ws3, wp3, wt3);
    } else if (i < O5) {
        int idx = i - O4;                 // 64*288, k = xb column
        int col = idx / 288, k = idx - col * 288;
        int row = (k < 6) ? k : k - 26;
        bool valid = (k < 6) || (k >= 32 && row < 262);
        w1t[idx] = f2b(valid ? w1[row * 64 + col] : 0.f);
    } else if (i < O6) {
        int e0 = (i - O5) * 4;            // 4 edges, independent atomic chains
        int d0 = ei[EE + e0],     d1 = ei[EE + e0 + 1];
        int d2 = ei[EE + e0 + 2], d3 = ei[EE + e0 + 3];
        int s0 = ei[e0],     s1 = ei[e0 + 1];
        int s2 = ei[e0 + 2], s3 = ei[e0 + 3];
        int p0 = atomicAdd(&deg[d0], 1);
        int p1 = atomicAdd(&deg[d1], 1);
        int p2 = atomicAdd(&deg[d2], 1);
        int p3 = atomicAdd(&deg[d3], 1);
        if (p0 < 16) ell[d0 * 16 + p0] = s0;
        else { int k = atomicAdd(ovfc, 1); ovf[2 * k] = d0; ovf[2 * k + 1] = s0; }
        if (p1 < 16) ell[d1 * 16 + p1] = s1;
        else { int k = atomicAdd(ovfc, 1); ovf[2 * k] = d1; ovf[2 * k + 1] = s1; }
        if (p2 < 16) ell[d2 * 16 + p2] = s2;
        else { int k = atomicAdd(ovfc, 1); ovf[2 * k] = d2; ovf[2 * k + 1] = s2; }
        if (p3 < 16) ell[d3 * 16 + p3] = s3;
        else { int k = atomicAdd(ovfc, 1); ovf[2 * k] = d3; ovf[2 * k + 1] = s3; }
    } else if (i < O7) {
        vg[(size_t)NN * 64 + (i - O6)] = 0u;     // dummy row: (P,PG) = (0,0)
    }
}

// ---------------- proj: MFMA 3-way, XOR-swizzled LDS weights ----------------
// P = 2^(-(a_src+p)*log2e), PG = P*(h-p) packed bf16|bf16 ; qh = half(p+b_pos).

template <int KP>
__global__ __launch_bounds__(256) void k_projm(
    const unsigned short* __restrict__ xb, const unsigned short* __restrict__ wt,
    const float* __restrict__ bpos,
    unsigned* __restrict__ vg, __half* __restrict__ qh) {
    __shared__ short wl[192 * 32];
    const int t = threadIdx.x;
    const int w = t >> 6, l = t & 63;
    const int lo = l & 15, hi = l >> 4;
    const int row_w = blockIdx.x * 128 + w * 32;

    f32x4 acc[2][12];
#pragma unroll
    for (int a = 0; a < 2; a++)
#pragma unroll
        for (int i = 0; i < 12; i++) acc[a][i] = (f32x4)0.f;

    const unsigned short* arow0 = xb + (size_t)(row_w + lo) * XSB;
    const unsigned short* arow1 = xb + (size_t)(row_w + 16 + lo) * XSB;
#pragma unroll
    for (int ks = 0; ks < KP / 32; ks++) {
        __syncthreads();
        {
            const uint4* src = (const uint4*)wt + (size_t)ks * 768;
            uint4* dst = (uint4*)wl;
#pragma unroll
            for (int i = 0; i < 3; i++) {
                int idx = i * 256 + t;
                dst[idx ^ ((idx >> 3) & 7)] = src[idx];
            }
        }
        __syncthreads();
        s16x8 af0 = *(const s16x8*)(arow0 + ks * 32 + hi * 8);
        s16x8 af1 = *(const s16x8*)(arow1 + ks * 32 + hi * 8);
#pragma unroll
        for (int ct = 0; ct < 12; ct++) {
            int ridx = (ct * 16 + lo) * 4 + hi;
            s16x8 bf = *(const s16x8*)&wl[(size_t)(ridx ^ ((ridx >> 3) & 7)) * 8];
            acc[0][ct] = __builtin_amdgcn_mfma_f32_16x16x32_bf16(af0, bf, acc[0][ct], 0, 0, 0);
            acc[1][ct] = __builtin_amdgcn_mfma_f32_16x16x32_bf16(af1, bf, acc[1][ct], 0, 0, 0);
        }
    }

#pragma unroll
    for (int tile = 0; tile < 2; tile++) {
#pragma unroll
        for (int r = 0; r < 4; r++) {
            int node = row_w + tile * 16 + hi * 4 + r;
            if (node < NN) {
#pragma unroll
                for (int j = 0; j < 4; j++) {
                    int c = j * 16 + lo;
                    float h  = acc[tile][0 + j][r];
                    float as = acc[tile][4 + j][r];
                    float p  = acc[tile][8 + j][r];
                    size_t o = (size_t)node * 64 + c;
                    float P = __builtin_amdgcn_exp2f(-(as + p) * LOG2E);
                    vg[o] = (unsigned)f2b(P) | ((unsigned)f2b(P * (h - p)) << 16);
                    qh[o] = __float2half(p + bpos[c]);
                }
            }
        }
    }
}

// ---------------- MFMA MLP-1 (262->64) fused with MLP-2 (64->10) ----------------

__global__ __launch_bounds__(256) void k_mlp1f(
    const unsigned short* __restrict__ xb, const unsigned short* __restrict__ w1t,
    const float* __restrict__ b1, const float* __restrict__ w2,
    const float* __restrict__ b2, float* __restrict__ out) {
    __shared__ float w2l[64][10];
    __shared__ float b2l[10];
    __shared__ float b1l[64];
    for (int t = threadIdx.x; t < 714; t += 256) {
        if (t < 640) ((float*)w2l)[t] = w2[t];
        else if (t < 650) b2l[t - 640] = b2[t - 640];
        else b1l[t - 650] = b1[t - 650];
    }
    __syncthreads();

    const int w = threadIdx.x >> 6, l = threadIdx.x & 63;
    const int lo = l & 15, hi = l >> 4;
    const int row_w = blockIdx.x * 256 + w * 64;

    f32x4 acc[4][4];
#pragma unroll
    for (int a = 0; a < 4; a++)
#pragma unroll
        for (int b = 0; b < 4; b++) acc[a][b] = (f32x4)0.f;

#pragma unroll
    for (int ks = 0; ks < 9; ks++) {
        const int k0 = ks * 32 + hi * 8;
        s16x8 bf[4];
#pragma unroll
        for (int ct = 0; ct < 4; ct++)
            bf[ct] = *(const s16x8*)(w1t + (size_t)(ct * 16 + lo) * 288 + k0);
#pragma unroll
        for (int rt = 0; rt < 4; rt++) {
            s16x8 af = *(const s16x8*)(xb + (size_t)(row_w + rt * 16 + lo) * XSB + k0);
#pragma unroll
            for (int ct = 0; ct < 4; ct++)
                acc[rt][ct] = __builtin_amdgcn_mfma_f32_16x16x32_bf16(af, bf[ct], acc[rt][ct], 0, 0, 0);
        }
    }

#pragma unroll
    for (int rt = 0; rt < 4; rt++) {
#pragma unroll
        for (int r = 0; r < 4; r++) {
            int node = row_w + rt * 16 + hi * 4 + r;
            float po[10];
#pragma unroll
            for (int o = 0; o < 10; o++) po[o] = 0.f;
#pragma unroll
            for (int ct = 0; ct < 4; ct++) {
                int c = ct * 16 + lo;
                float hv = acc[rt][ct][r] + b1l[c];
#pragma unroll
                for (int o = 0; o < 10; o++) po[o] = fmaf(hv, w2l[c][o], po[o]);
            }
#pragma unroll
            for (int m = 1; m < 16; m <<= 1)
#pragma unroll
                for (int o = 0; o < 10; o++) po[o] += __shfl_xor(po[o], m);
            if (lo == 0 && node < NN) {
                float* op = out + (size_t)node * 10;
#pragma unroll
                for (int o = 0; o < 5; o++)
                    *(float2*)(op + o * 2) = make_float2(po[o * 2] + b2l[o * 2],
                                                         po[o * 2 + 1] + b2l[o * 2 + 1]);
            }
        }
    }
}

// ---------------- edge aggregation: group-per-node, ELL adjacency ----------------

template <int RELU>
__global__ __launch_bounds__(256) void k_edge(
    const uint4* __restrict__ vg,     // [NN+1][16] uint4 = 64 channels of bf16(P)|bf16(PG)<<16
    const uint2* __restrict__ qh,     // [NN][16] uint2 = 64 channels of half q
    const int* __restrict__ deg, const int* __restrict__ ell,
    const int* __restrict__ ovfc, const int* __restrict__ ovf,
    unsigned short* __restrict__ xb, int col) {
    int l = threadIdx.x & 63;
    int g = l >> 4, lg = l & 15, gbase = g * 16;
    int node = (blockIdx.x * 4 + (threadIdx.x >> 6)) * 4 + g;   // NN % 16 == 0
    int dg = deg[node];
    int pre = ell[node * 16 + lg];                         // aligned 64B group read
    uint2 qr = qh[(size_t)node * 16 + lg];                 // overlaps with pre load
    float d[4] = {0.f, 0.f, 0.f, 0.f};
    float s[4] = {0.f, 0.f, 0.f, 0.f};

    int degc = min(dg, 16);
    for (int it = 0; it < degc; it += 4) {
        int i0 = (it < dg)     ? __shfl(pre, gbase + it)     : NN;
        int i1 = (it + 1 < dg) ? __shfl(pre, gbase + it + 1) : NN;
        int i2 = (it + 2 < dg) ? __shfl(pre, gbase + it + 2) : NN;
        int i3 = (it + 3 < dg) ? __shfl(pre, gbase + it + 3) : NN;
        uint4 r0 = vg[(size_t)i0 * 16 + lg];
        uint4 r1 = vg[(size_t)i1 * 16 + lg];
        uint4 r2 = vg[(size_t)i2 * 16 + lg];
        uint4 r3 = vg[(size_t)i3 * 16 + lg];
        accum4(d, s, r0); accum4(d, s, r1); accum4(d, s, r2); accum4(d, s, r3);
    }
    if (dg > 16) {                                         // rare tail via overflow list
        int cnt = ovfc[0];
        for (int i = 0; i < cnt; i++) {
            if (ovf[2 * i] == node) {
                uint4 r0 = vg[(size_t)ovf[2 * i + 1] * 16 + lg];
                accum4(d, s, r0);
            }
        }
    }

    float2 q01 = __half22float2(*(const __half2*)&qr.x);
    float2 q23 = __half22float2(*(const __half2*)&qr.y);
    float qv[4] = {q01.x, q01.y, q23.x, q23.y};
    float o[4];
#pragma unroll
    for (int ch = 0; ch < 4; ch++) {
        float v = (s[ch] + qv[ch] * d[ch]) / (d[ch] + 1e-16f);
        if (RELU) v = (v > 0.f) ? v : 0.01f * v;
        o[ch] = v;
    }
    unsigned p01 = (unsigned)f2b(o[0]) | ((unsigned)f2b(o[1]) << 16);
    unsigned p23 = (unsigned)f2b(o[2]) | ((unsigned)f2b(o[3]) << 16);
    *(uint2*)(xb + (size_t)node * XSB + col + 4 * lg) = make_uint2(p01, p23);
}

// ---------------- launch ----------------

extern "C" void kernel_launch(void* const* d_in, const int* in_sizes, int n_in,
                              void* d_out, int out_size, void* d_ws, size_t ws_size,
                              hipStream_t stream) {
    const float* x = (const float*)d_in[0];
    const int* ei = (const int*)d_in[1];
    const float* W[4][4];
    const float* BP[4];
    int base = 2;
    for (int l = 0; l < 4; l++) {
        for (int m = 0; m < 4; m++) W[l][m] = (const float*)d_in[base + m];
        BP[l] = (const float*)d_in[base + 4];
        base += 5;
    }
    const float* w1 = (const float*)d_in[22];
    const float* b1 = (const float*)d_in[23];
    const float* w2 = (const float*)d_in[24];
    const float* b2 = (const float*)d_in[25];

    char* wsp = (char*)d_ws;
    size_t off = 0;
    auto alloc = [&](size_t bytes) {
        void* p = wsp + off;
        off += (bytes + 255) & ~(size_t)255;
        return p;
    };
    unsigned short* xb = (unsigned short*)alloc((size_t)(NN + 256) * XSB * 2);
    unsigned* vg = (unsigned*)alloc((size_t)(NN + 1) * 64 * 4);   // +1 dummy row
    __half* qh = (__half*)alloc((size_t)NN * 64 * 2);
    int* deg = (int*)alloc((size_t)NN * 4);       // deg (padded 400128) then ovfc: one memset
    int* ovfc = (int*)alloc(256);
    int* ell = (int*)alloc((size_t)NN * 16 * 4);
    int* ovf = (int*)alloc((size_t)2 * EE * 4);
    const int KPv[4] = {32, 96, 160, 224};
    unsigned short* wt[4];
    for (int l = 0; l < 4; l++) wt[l] = (unsigned short*)alloc((size_t)192 * KPv[l] * 2);
    unsigned short* w1t = (unsigned short*)alloc((size_t)64 * 288 * 2);

    // zero deg (400000B -> padded 400128) + ovfc (256B) in one memset
    hipMemsetAsync(deg, 0, 400128 + 256, stream);
    k_setup<<<(O7 + 255) / 256, 256, 0, stream>>>(
        x, ei,
        W[0][0], W[0][1], W[0][3],
        W[1][0], W[1][1], W[1][3],
        W[2][0], W[2][1], W[2][3],
        W[3][0], W[3][1], W[3][3], w1,
        xb, wt[0], wt[1], wt[2], wt[3], w1t, deg, ell, ovfc, ovf, vg);

    const int gProj = (NN + 127) / 128;  // 782
    const int gEdge = NN / 16;           // 6250 (NN % 16 == 0)
    const uint4* vgu = (const uint4*)vg;
    const uint2* qh2 = (const uint2*)qh;

    k_projm<32><<<gProj, 256, 0, stream>>>(xb, wt[0], BP[0], vg, qh);
    k_edge<0><<<gEdge, 256, 0, stream>>>(vgu, qh2, deg, ell, ovfc, ovf, xb, 32);
    k_projm<96><<<gProj, 256, 0, stream>>>(xb, wt[1], BP[1], vg, qh);
    k_edge<1><<<gEdge, 256, 0, stream>>>(vgu, qh2, deg, ell, ovfc, ovf, xb, 96);
    k_projm<160><<<gProj, 256, 0, stream>>>(xb, wt[2], BP[2], vg, qh);
    k_edge<1><<<gEdge, 256, 0, stream>>>(vgu, qh2, deg, ell, ovfc, ovf, xb, 160);
    k_projm<224><<<gProj, 256, 0, stream>>>(xb, wt[3], BP[3], vg, qh);
    k_edge<1><<<gEdge, 256, 0, stream>>>(vgu, qh2, deg, ell, ovfc, ovf, xb, 224);

    k_mlp1f<<<(NN + 255) / 256, 256, 0, stream>>>(xb, w1t, b1, w2, b2, (float*)d_out);
}

// Round 23
// 267.339 us; speedup vs baseline: 1.1236x; 1.0015x over previous
//
#include <hip/hip_runtime.h>
#include <hip/hip_fp16.h>

#define NN 100000
#define EE 600000
#define XSB 288          // bf16 feature row stride; layout: [x(6)|pad(26)|x1|x2|x3|x4], 64B-aligned
#define LOG2E 1.44269504f

typedef __attribute__((ext_vector_type(8))) short s16x8;
typedef __attribute__((ext_vector_type(4))) float f32x4;

__device__ inline unsigned short f2b(float f) {   // fp32 -> bf16 RNE
    unsigned u = __float_as_uint(f);
    u += 0x7fffu + ((u >> 16) & 1u);
    return (unsigned short)(u >> 16);
}

__device__ inline void accum4(float* d, float* s, const uint4& r) {
    const unsigned* u = (const unsigned*)&r;
#pragma unroll
    for (int ch = 0; ch < 4; ch++) {
        d[ch] += __uint_as_float(u[ch] << 16);
        s[ch] += __uint_as_float(u[ch] & 0xFFFF0000u);
    }
}

// xb-column k -> weight row: k<6 -> k ; k>=32 -> k-26 ; pad band [6,32) zero.
__device__ inline void wconv_elem(int idx, int fin,
                                  const float* wlin, const float* wsrc,
                                  const float* wpos, unsigned short* wt) {
    int ks = idx / 6144;          // 192*32
    int rem = idx - ks * 6144;
    int col = rem >> 5, kk = rem & 31;
    int k = ks * 32 + kk;
    int row = (k < 6) ? k : k - 26;
    float val = 0.f;
    if (k < 6 || (k >= 32 && row < fin)) {
        int m = col >> 6, c = col & 63;
        const float* W = (m == 0) ? wlin : (m == 1) ? wsrc : wpos;
        val = W[row * 64 + c];
    }
    wt[idx] = f2b(val);
}

// ---------------- fused setup: ELL build FIRST (8 edges/thread), then cheap ranges ----------
// The ELL range's long-latency atomic-chain waves launch first and stay resident while
// the ~3300 cheap blocks (xb init, weight conversion) flood behind them — overlapping
// the chain stalls (r22 profiled the tail at 20% occupancy when ELL was last).
// deg + ovfc zeroed by hipMemsetAsync before this kernel.
#define A0 75000                  // EE/8: ELL build, 8 edges/thread
#define A1 875000                 // +100k*8: xb init (4 cols/thread, uint2 store)
#define A2 881144                 // +192*32   wt0
#define A3 899576                 // +192*96   wt1
#define A4 930296                 // +192*160  wt2
#define A5 973304                 // +192*224  wt3
#define A6 991736                 // +64*288   w1t
#define A7 991800                 // +64       dummy vg row

__global__ __launch_bounds__(256) void k_setup(
    const float* __restrict__ x, const int* __restrict__ ei,
    const float* __restrict__ wl0, const float* __restrict__ ws0, const float* __restrict__ wp0,
    const float* __restrict__ wl1, const float* __restrict__ ws1, const float* __restrict__ wp1,
    const float* __restrict__ wl2, const float* __restrict__ ws2, const float* __restrict__ wp2,
    const float* __restrict__ wl3, const float* __restrict__ ws3, const float* __restrict__ wp3,
    const float* __restrict__ w1,
    unsigned short* __restrict__ xb,
    unsigned short* __restrict__ wt0, unsigned short* __restrict__ wt1,
    unsigned short* __restrict__ wt2, unsigned short* __restrict__ wt3,
    unsigned short* __restrict__ w1t, int* __restrict__ deg,
    int* __restrict__ ell, int* __restrict__ ovfc, int* __restrict__ ovf,
    unsigned* __restrict__ vg) {
    int i = blockIdx.x * 256 + threadIdx.x;
    if (i < A0) {
        int e0 = i * 8;                   // 8 edges, independent atomic chains
        int d[8], sv[8], p[8];
#pragma unroll
        for (int k = 0; k < 8; k++) {     // 16 coalesced loads
            d[k] = ei[EE + e0 + k];
            sv[k] = ei[e0 + k];
        }
#pragma unroll
        for (int k = 0; k < 8; k++) p[k] = atomicAdd(&deg[d[k]], 1);
#pragma unroll
        for (int k = 0; k < 8; k++) {
            if (p[k] < 16) {
                ell[d[k] * 16 + p[k]] = sv[k];
            } else {                      // rare: deg > 16 (P ~ 1e-4 per node)
                int kk = atomicAdd(ovfc, 1);
                ovf[2 * kk] = d[k];
                ovf[2 * kk + 1] = sv[k];
            }
        }
    } else if (i < A1) {
        int idx = i - A0;
        int n = idx >> 3, c = (idx & 7) * 4;   // cols c..c+3 (8B-aligned)
        unsigned v0 = 0u, v1 = 0u;
        if (c < 6) {
            v0 = (unsigned)f2b(x[n * 6 + c]) |
                 ((c + 1 < 6 ? (unsigned)f2b(x[n * 6 + c + 1]) : 0u) << 16);
            if (c + 2 < 6)
                v1 = (unsigned)f2b(x[n * 6 + c + 2]) |
                     ((c + 3 < 6 ? (unsigned)f2b(x[n * 6 + c + 3]) : 0u) << 16);
        }
        *(uint2*)&xb[(size_t)n * XSB + c] = make_uint2(v0, v1);
    } else if (i < A2) {
        wconv_elem(i - A1, 6, wl0, ws0, wp0, wt0);
    } else if (i < A3) {
        wconv_elem(i - A2, 70, wl1, ws1, wp1, wt1);
    } else if (i < A4) {
        wconv_elem(i - A3, 134, wl2, ws2, wp2, wt2);
    } else if (i < A5) {
        wconv_elem(i - A4, 198, wl3, ws3, wp3, wt3);
    } else if (i < A6) {
        int idx = i - A5;                 // 64*288, k = xb column
        int col = idx / 288, k = idx - col * 288;
        int row = (k < 6) ? k : k - 26;
        bool valid = (k < 6) || (k >= 32 && row < 262);
        w1t[idx] = f2b(valid ? w1[row * 64 + col] : 0.f);
    } else if (i < A7) {
        vg[(size_t)NN * 64 + (i - A6)] = 0u;     // dummy row: (P,PG) = (0,0)
    }
}

// ---------------- proj: MFMA 3-way, XOR-swizzled LDS weights ----------------
// P = 2^(-(a_src+p)*log2e), PG = P*(h-p) packed bf16|bf16 ; qh = half(p+b_pos).

template <int KP>
__global__ __launch_bounds__(256) void k_projm(
    const unsigned short* __restrict__ xb, const unsigned short* __restrict__ wt,
    const float* __restrict__ bpos,
    unsigned* __restrict__ vg, __half* __restrict__ qh) {
    __shared__ short wl[192 * 32];
    const int t = threadIdx.x;
    const int w = t >> 6, l = t & 63;
    const int lo = l & 15, hi = l >> 4;
    const int row_w = blockIdx.x * 128 + w * 32;

    f32x4 acc[2][12];
#pragma unroll
    for (int a = 0; a < 2; a++)
#pragma unroll
        for (int i = 0; i < 12; i++) acc[a][i] = (f32x4)0.f;

    const unsigned short* arow0 = xb + (size_t)(row_w + lo) * XSB;
    const unsigned short* arow1 = xb + (size_t)(row_w + 16 + lo) * XSB;
#pragma unroll
    for (int ks = 0; ks < KP / 32; ks++) {
        __syncthreads();
        {
            const uint4* src = (const uint4*)wt + (size_t)ks * 768;
            uint4* dst = (uint4*)wl;
#pragma unroll
            for (int i = 0; i < 3; i++) {
                int idx = i * 256 + t;
                dst[idx ^ ((idx >> 3) & 7)] = src[idx];
            }
        }
        __syncthreads();
        s16x8 af0 = *(const s16x8*)(arow0 + ks * 32 + hi * 8);
        s16x8 af1 = *(const s16x8*)(arow1 + ks * 32 + hi * 8);
#pragma unroll
        for (int ct = 0; ct < 12; ct++) {
            int ridx = (ct * 16 + lo) * 4 + hi;
            s16x8 bf = *(const s16x8*)&wl[(size_t)(ridx ^ ((ridx >> 3) & 7)) * 8];
            acc[0][ct] = __builtin_amdgcn_mfma_f32_16x16x32_bf16(af0, bf, acc[0][ct], 0, 0, 0);
            acc[1][ct] = __builtin_amdgcn_mfma_f32_16x16x32_bf16(af1, bf, acc[1][ct], 0, 0, 0);
        }
    }

#pragma unroll
    for (int tile = 0; tile < 2; tile++) {
#pragma unroll
        for (int r = 0; r < 4; r++) {
            int node = row_w + tile * 16 + hi * 4 + r;
            if (node < NN) {
#pragma unroll
                for (int j = 0; j < 4; j++) {
                    int c = j * 16 + lo;
                    float h  = acc[tile][0 + j][r];
                    float as = acc[tile][4 + j][r];
                    float p  = acc[tile][8 + j][r];
                    size_t o = (size_t)node * 64 + c;
                    float P = __builtin_amdgcn_exp2f(-(as + p) * LOG2E);
                    vg[o] = (unsigned)f2b(P) | ((unsigned)f2b(P * (h - p)) << 16);
                    qh[o] = __float2half(p + bpos[c]);
                }
            }
        }
    }
}

// ---------------- MFMA MLP-1 (262->64) fused with MLP-2 (64->10) ----------------

__global__ __launch_bounds__(256) void k_mlp1f(
    const unsigned short* __restrict__ xb, const unsigned short* __restrict__ w1t,
    const float* __restrict__ b1, const float* __restrict__ w2,
    const float* __restrict__ b2, float* __restrict__ out) {
    __shared__ float w2l[64][10];
    __shared__ float b2l[10];
    __shared__ float b1l[64];
    for (int t = threadIdx.x; t < 714; t += 256) {
        if (t < 640) ((float*)w2l)[t] = w2[t];
        else if (t < 650) b2l[t - 640] = b2[t - 640];
        else b1l[t - 650] = b1[t - 650];
    }
    __syncthreads();

    const int w = threadIdx.x >> 6, l = threadIdx.x & 63;
    const int lo = l & 15, hi = l >> 4;
    const int row_w = blockIdx.x * 256 + w * 64;

    f32x4 acc[4][4];
#pragma unroll
    for (int a = 0; a < 4; a++)
#pragma unroll
        for (int b = 0; b < 4; b++) acc[a][b] = (f32x4)0.f;

#pragma unroll
    for (int ks = 0; ks < 9; ks++) {
        const int k0 = ks * 32 + hi * 8;
        s16x8 bf[4];
#pragma unroll
        for (int ct = 0; ct < 4; ct++)
            bf[ct] = *(const s16x8*)(w1t + (size_t)(ct * 16 + lo) * 288 + k0);
#pragma unroll
        for (int rt = 0; rt < 4; rt++) {
            s16x8 af = *(const s16x8*)(xb + (size_t)(row_w + rt * 16 + lo) * XSB + k0);
#pragma unroll
            for (int ct = 0; ct < 4; ct++)
                acc[rt][ct] = __builtin_amdgcn_mfma_f32_16x16x32_bf16(af, bf[ct], acc[rt][ct], 0, 0, 0);
        }
    }

#pragma unroll
    for (int rt = 0; rt < 4; rt++) {
#pragma unroll
        for (int r = 0; r < 4; r++) {
            int node = row_w + rt * 16 + hi * 4 + r;
            float po[10];
#pragma unroll
            for (int o = 0; o < 10; o++) po[o] = 0.f;
#pragma unroll
            for (int ct = 0; ct < 4; ct++) {
                int c = ct * 16 + lo;
                float hv = acc[rt][ct][r] + b1l[c];
#pragma unroll
                for (int o = 0; o < 10; o++) po[o] = fmaf(hv, w2l[c][o], po[o]);
            }
#pragma unroll
            for (int m = 1; m < 16; m <<= 1)
#pragma unroll
                for (int o = 0; o < 10; o++) po[o] += __shfl_xor(po[o], m);
            if (lo == 0 && node < NN) {
                float* op = out + (size_t)node * 10;
#pragma unroll
                for (int o = 0; o < 5; o++)
                    *(float2*)(op + o * 2) = make_float2(po[o * 2] + b2l[o * 2],
                                                         po[o * 2 + 1] + b2l[o * 2 + 1]);
            }
        }
    }
}

// ---------------- edge aggregation: group-per-node, ELL adjacency ----------------

template <int RELU>
__global__ __launch_bounds__(256) void k_edge(
    const uint4* __restrict__ vg,     // [NN+1][16] uint4 = 64 channels of bf16(P)|bf16(PG)<<16
    const uint2* __restrict__ qh,     // [NN][16] uint2 = 64 channels of half q
    const int* __restrict__ deg, const int* __restrict__ ell,
    const int* __restrict__ ovfc, const int* __restrict__ ovf,
    unsigned short* __restrict__ xb, int col) {
    int l = threadIdx.x & 63;
    int g = l >> 4, lg = l & 15, gbase = g * 16;
    int node = (blockIdx.x * 4 + (threadIdx.x >> 6)) * 4 + g;   // NN % 16 == 0
    int dg = deg[node];
    int pre = ell[node * 16 + lg];                         // aligned 64B group read
    uint2 qr = qh[(size_t)node * 16 + lg];                 // overlaps with pre load
    float d[4] = {0.f, 0.f, 0.f, 0.f};
    float s[4] = {0.f, 0.f, 0.f, 0.f};

    int degc = min(dg, 16);
    for (int it = 0; it < degc; it += 4) {
        int i0 = (it < dg)     ? __shfl(pre, gbase + it)     : NN;
        int i1 = (it + 1 < dg) ? __shfl(pre, gbase + it + 1) : NN;
        int i2 = (it + 2 < dg) ? __shfl(pre, gbase + it + 2) : NN;
        int i3 = (it + 3 < dg) ? __shfl(pre, gbase + it + 3) : NN;
        uint4 r0 = vg[(size_t)i0 * 16 + lg];
        uint4 r1 = vg[(size_t)i1 * 16 + lg];
        uint4 r2 = vg[(size_t)i2 * 16 + lg];
        uint4 r3 = vg[(size_t)i3 * 16 + lg];
        accum4(d, s, r0); accum4(d, s, r1); accum4(d, s, r2); accum4(d, s, r3);
    }
    if (dg > 16) {                                         // rare tail via overflow list
        int cnt = ovfc[0];
        for (int i = 0; i < cnt; i++) {
            if (ovf[2 * i] == node) {
                uint4 r0 = vg[(size_t)ovf[2 * i + 1] * 16 + lg];
                accum4(d, s, r0);
            }
        }
    }

    float2 q01 = __half22float2(*(const __half2*)&qr.x);
    float2 q23 = __half22float2(*(const __half2*)&qr.y);
    float qv[4] = {q01.x, q01.y, q23.x, q23.y};
    float o[4];
#pragma unroll
    for (int ch = 0; ch < 4; ch++) {
        float v = (s[ch] + qv[ch] * d[ch]) / (d[ch] + 1e-16f);
        if (RELU) v = (v > 0.f) ? v : 0.01f * v;
        o[ch] = v;
    }
    unsigned p01 = (unsigned)f2b(o[0]) | ((unsigned)f2b(o[1]) << 16);
    unsigned p23 = (unsigned)f2b(o[2]) | ((unsigned)f2b(o[3]) << 16);
    *(uint2*)(xb + (size_t)node * XSB + col + 4 * lg) = make_uint2(p01, p23);
}

// ---------------- launch ----------------

extern "C" void kernel_launch(void* const* d_in, const int* in_sizes, int n_in,
                              void* d_out, int out_size, void* d_ws, size_t ws_size,
                              hipStream_t stream) {
    const float* x = (const float*)d_in[0];
    const int* ei = (const int*)d_in[1];
    const float* W[4][4];
    const float* BP[4];
    int base = 2;
    for (int l = 0; l < 4; l++) {
        for (int m = 0; m < 4; m++) W[l][m] = (const float*)d_in[base + m];
        BP[l] = (const float*)d_in[base + 4];
        base += 5;
    }
    const float* w1 = (const float*)d_in[22];
    const float* b1 = (const float*)d_in[23];
    const float* w2 = (const float*)d_in[24];
    const float* b2 = (const float*)d_in[25];

    char* wsp = (char*)d_ws;
    size_t off = 0;
    auto alloc = [&](size_t bytes) {
        void* p = wsp + off;
        off += (bytes + 255) & ~(size_t)255;
        return p;
    };
    unsigned short* xb = (unsigned short*)alloc((size_t)(NN + 256) * XSB * 2);
    unsigned* vg = (unsigned*)alloc((size_t)(NN + 1) * 64 * 4);   // +1 dummy row
    __half* qh = (__half*)alloc((size_t)NN * 64 * 2);
    int* deg = (int*)alloc((size_t)NN * 4);       // deg (padded 400128) then ovfc: one memset
    int* ovfc = (int*)alloc(256);
    int* ell = (int*)alloc((size_t)NN * 16 * 4);
    int* ovf = (int*)alloc((size_t)2 * EE * 4);
    const int KPv[4] = {32, 96, 160, 224};
    unsigned short* wt[4];
    for (int l = 0; l < 4; l++) wt[l] = (unsigned short*)alloc((size_t)192 * KPv[l] * 2);
    unsigned short* w1t = (unsigned short*)alloc((size_t)64 * 288 * 2);

    // zero deg (400000B -> padded 400128) + ovfc (256B) in one memset
    hipMemsetAsync(deg, 0, 400128 + 256, stream);
    k_setup<<<(A7 + 255) / 256, 256, 0, stream>>>(
        x, ei,
        W[0][0], W[0][1], W[0][3],
        W[1][0], W[1][1], W[1][3],
        W[2][0], W[2][1], W[2][3],
        W[3][0], W[3][1], W[3][3], w1,
        xb, wt[0], wt[1], wt[2], wt[3], w1t, deg, ell, ovfc, ovf, vg);

    const int gProj = (NN + 127) / 128;  // 782
    const int gEdge = NN / 16;           // 6250 (NN % 16 == 0)
    const uint4* vgu = (const uint4*)vg;
    const uint2* qh2 = (const uint2*)qh;

    k_projm<32><<<gProj, 256, 0, stream>>>(xb, wt[0], BP[0], vg, qh);
    k_edge<0><<<gEdge, 256, 0, stream>>>(vgu, qh2, deg, ell, ovfc, ovf, xb, 32);
    k_projm<96><<<gProj, 256, 0, stream>>>(xb, wt[1], BP[1], vg, qh);
    k_edge<1><<<gEdge, 256, 0, stream>>>(vgu, qh2, deg, ell, ovfc, ovf, xb, 96);
    k_projm<160><<<gProj, 256, 0, stream>>>(xb, wt[2], BP[2], vg, qh);
    k_edge<1><<<gEdge, 256, 0, stream>>>(vgu, qh2, deg, ell, ovfc, ovf, xb, 160);
    k_projm<224><<<gProj, 256, 0, stream>>>(xb, wt[3], BP[3], vg, qh);
    k_edge<1><<<gEdge, 256, 0, stream>>>(vgu, qh2, deg, ell, ovfc, ovf, xb, 224);

    k_mlp1f<<<(NN + 255) / 256, 256, 0, stream>>>(xb, w1t, b1, w2, b2, (float*)d_out);
}